// Round 11
// baseline (72.212 us; speedup 1.0000x reference)
//
#include <hip/hip_runtime.h>
#include <math.h>

#define B 1000
#define D 8
#define PRE 98
#define NEXT 512
#define SC 32
#define ANT 5
#define BM 16
#define NBLK 63           // 63 * 16 = 1008 >= 1000
#define KP 128            // PRE padded to 128 for MFMA K-steps

// tail-weight LDS layout (floats)
#define OW3 0
#define OW4 3136
#define OWO 7938
#define OB3 8428
#define OB4 8526
#define OBO 8575
#define WTOT 8585

using bf16x8 = __attribute__((ext_vector_type(8))) short;
using f32x4  = __attribute__((ext_vector_type(4))) float;

static __device__ __forceinline__ unsigned short f2bf(float f) {
    union { float f; unsigned u; } v{f};
    unsigned r = (v.u + 0x7fffu + ((v.u >> 16) & 1u)) >> 16;
    return (unsigned short)r;
}
static __device__ __forceinline__ float bf2f(unsigned short h) {
    union { unsigned u; float f; } v{(unsigned)h << 16};
    return v.f;
}

// ---------------------------------------------------------------------------
// Prep: transpose/convert weights to bf16:
//   sub_wT[d][n][k] (k padded to 128 with 0) = sub_w[d][k][n]
//   cut_wT[d][c][k]                          = cut_w[d][k][c]
// ---------------------------------------------------------------------------
__global__ __launch_bounds__(256) void k_prep(const float* __restrict__ sub_w,
                                              const float* __restrict__ cut_w,
                                              unsigned short* __restrict__ sub_wT,
                                              unsigned short* __restrict__ cut_wT) {
    __shared__ __align__(16) unsigned short tile[32][128];
    int t = threadIdx.x, bid = blockIdx.x;
    if (bid < 128) {                       // sub_w: (d, n-tile of 32), k = 0..127
        int d = bid >> 4, n0 = (bid & 15) * 32;
        int nn = t & 31, kk = t >> 5;      // kk 0..7
#pragma unroll
        for (int j = 0; j < 16; ++j) {
            int k = j * 8 + kk;
            float v = (k < PRE) ? sub_w[(d * PRE + k) * NEXT + n0 + nn] : 0.f;
            tile[nn][k] = f2bf(v);
        }
        __syncthreads();
        int row = t >> 3, c0 = (t & 7) * 16;
        unsigned short* dst = sub_wT + ((size_t)(d * NEXT + n0 + row)) * KP + c0;
        *reinterpret_cast<bf16x8*>(dst)     = *reinterpret_cast<bf16x8*>(&tile[row][c0]);
        *reinterpret_cast<bf16x8*>(dst + 8) = *reinterpret_cast<bf16x8*>(&tile[row][c0 + 8]);
    } else {                               // cut_w: (d, k-chunk of 128)
        int bb = bid - 128;                // 0..31
        int d = bb >> 2, k0 = (bb & 3) * 128;
        int nn = t & 31, kk = t >> 5;
#pragma unroll
        for (int j = 0; j < 16; ++j) {
            int kl = j * 8 + kk;
            tile[nn][kl] = f2bf(cut_w[(d * NEXT + k0 + kl) * SC + nn]);
        }
        __syncthreads();
        int row = t >> 3, c0 = (t & 7) * 16;
        unsigned short* dst = cut_wT + ((size_t)(d * SC + row)) * NEXT + k0 + c0;
        *reinterpret_cast<bf16x8*>(dst)     = *reinterpret_cast<bf16x8*>(&tile[row][c0]);
        *reinterpret_cast<bf16x8*>(dst + 8) = *reinterpret_cast<bf16x8*>(&tile[row][c0 + 8]);
    }
}

// ---------------------------------------------------------------------------
// k_mega: ONE block per 16-row tile (63 blocks, 512 thr = 8 waves).
// Loops d = 0..7 internally with double-buffered B-panel prefetch:
//   [issue bq(d+1), gq(d)] -> barrier -> GEMM1(d) -> h -> barrier -> LN ->
//   barrier -> GEMM2(d) (waves 0-3, K-split 2-way) -> barrier ->
//   z_lds += relu(.)*coef  (waves 0-1)
// Then the tail MLP + log_softmax for its own 16 rows. NO cross-block
// communication, no part buffer, no atomics, no spin.
// MFMA 16x16x32 bf16 layouts (m89/m91-verified):
//   A[m][k]: m = lane&15, k = (lane>>4)*8 + j   (8 contiguous bf16 = 16B)
//   B[k][n]: n = lane&15, k = (lane>>4)*8 + j
//   D[m][n]: n = lane&15, m = (lane>>4)*4 + reg
// ---------------------------------------------------------------------------
__global__ __launch_bounds__(512) void k_mega(const float* __restrict__ x,
                                              const unsigned short* __restrict__ sub_wT,
                                              const float* __restrict__ sub_b,
                                              const float* __restrict__ gamma,
                                              const float* __restrict__ beta,
                                              const unsigned short* __restrict__ cut_wT,
                                              const float* __restrict__ cut_b,
                                              const float* __restrict__ b_mat,
                                              const float* __restrict__ h_mat,
                                              const float* __restrict__ a_mat,
                                              const int* __restrict__ k_idx,
                                              const float* __restrict__ noise,
                                              const float* __restrict__ clb,
                                              const float* __restrict__ fc3_w,
                                              const float* __restrict__ fc3_b,
                                              const float* __restrict__ fc4_w,
                                              const float* __restrict__ fc4_b,
                                              const float* __restrict__ out_w,
                                              const float* __restrict__ out_b,
                                              float* __restrict__ out) {
    __shared__ __align__(16) unsigned short x_lds[D][BM][136]; // 34816 B
    __shared__ __align__(16) unsigned short h_lds[BM][536];    // 17152 B
    __shared__ float z_lds[BM][SC];                            //  2048 B
    __shared__ f32x4 pacc[4][64];                              //  4096 B
    __shared__ float W_lds[WTOT];                              // 34340 B
    __shared__ float coef_s[D][SC], cutb_s[D][SC];             //  2048 B
    __shared__ float clb_s[SC], am_s[SC * ANT];
    __shared__ float z3_s[BM][98];                             //  6272 B
    __shared__ float z4_s[BM][52];                             //  3328 B

    int t = threadIdx.x;
    int b0 = blockIdx.x * BM;
    int w = t >> 6, lane = t & 63;
    int lr = lane >> 4, lc = lane & 15;

    // ---- issue d=0 B-panel loads first (hide under all staging below) ----
    const unsigned short* bw_base = sub_wT + (size_t)(w * 64 + lc) * KP + lr * 8;
    bf16x8 bqA[4][4], bqB[4][4];
#pragma unroll
    for (int ks = 0; ks < 4; ++ks)
#pragma unroll
        for (int nf = 0; nf < 4; ++nf)
            bqA[ks][nf] = *reinterpret_cast<const bf16x8*>(
                bw_base + (size_t)nf * 16 * KP + ks * 32);

    // ---- stage x: 16 rows x 784 cols, float4-coalesced, split by d ----
    for (int idx = t; idx < BM * 196; idx += 512) {
        int r = idx / 196, q = idx - r * 196;
        int b = b0 + r;
        float4 v = (b < B) ? *reinterpret_cast<const float4*>(x + (size_t)b * (D * PRE) + q * 4)
                           : float4{0.f, 0.f, 0.f, 0.f};
        int jj = q * 4;
        int dd = jj / 98, ii = jj - dd * 98;
        float vv[4] = {v.x, v.y, v.z, v.w};
#pragma unroll
        for (int e = 0; e < 4; ++e) {
            x_lds[dd][r][ii] = f2bf(vv[e]);
            if (++ii == 98) { ii = 0; ++dd; }
        }
    }
    // zero the k-pad region [98,136) (disjoint from stage writes, no barrier)
    for (int i = t; i < D * BM * 19; i += 512) {
        int dr = i / 19, rem = i - dr * 19;
        reinterpret_cast<unsigned int*>(&x_lds[dr >> 4][dr & 15][98])[rem] = 0u;
    }
    // zero z accumulator (16*32 = 512: one element each)
    reinterpret_cast<float*>(z_lds)[t] = 0.f;
    // stage tail weights + constants
    for (int i = t; i < 3136; i += 512) W_lds[OW3 + i] = fc3_w[i];
    for (int i = t; i < 4802; i += 512) W_lds[OW4 + i] = fc4_w[i];
    for (int i = t; i < 490; i += 512)  W_lds[OWO + i] = out_w[i];
    if (t < 98) W_lds[OB3 + t] = fc3_b[t];
    if (t < 49) W_lds[OB4 + t] = fc4_b[t];
    if (t < 10) W_lds[OBO + t] = out_b[t];
    if (t >= 128 && t < 128 + SC) clb_s[t - 128] = clb[t - 128];
    if (t >= 192 && t < 192 + SC * ANT) am_s[t - 192] = a_mat[t - 192];
    // coef/cutb for all (d, c)
    if (t < D * SC) {
        int d = t >> 5, c = t & 31;
        int kk = k_idx[c];
        float hv = 0.f;
#pragma unroll
        for (int a = 0; a < ANT; ++a)
            hv = fmaf(h_mat[(d * SC + kk) * ANT + a], a_mat[c * ANT + a], hv);
        coef_s[d][c] = b_mat[d * SC + c] * hv;
        cutb_s[d][c] = cut_b[d * SC + c];
    }

    // ---- per-d body (cur = this d's B-panel; nxt filled if prefetch) ----
    auto body = [&](int d, bf16x8 (&cur)[4][4], bf16x8 (&nxt)[4][4], bool prefetch) {
        if (prefetch) {
#pragma unroll
            for (int ks = 0; ks < 4; ++ks)
#pragma unroll
                for (int nf = 0; nf < 4; ++nf)
                    nxt[ks][nf] = *reinterpret_cast<const bf16x8*>(
                        bw_base + (size_t)(d + 1) * NEXT * KP + (size_t)nf * 16 * KP + ks * 32);
        }
        // GEMM2 B-fragments for THIS d (waves 0-3); used after LN
        bf16x8 gq[8];
        if (w < 4) {
            const unsigned short* cw = cut_wT + (size_t)(d * SC + (w & 1) * 16 + lc) * NEXT
                                       + (w >> 1) * 256 + lr * 8;
#pragma unroll
            for (int ks = 0; ks < 8; ++ks)
                gq[ks] = *reinterpret_cast<const bf16x8*>(cw + ks * 32);
        }
        __syncthreads();   // (a) x ready / h free / pacc & z consumed

        // GEMM1: (16x128)@(128x512); wave -> 16 rows x 64 cols
        f32x4 acc[4] = {};
#pragma unroll
        for (int ks = 0; ks < 4; ++ks) {
            bf16x8 a0 = *reinterpret_cast<const bf16x8*>(&x_lds[d][lc][ks * 32 + lr * 8]);
#pragma unroll
            for (int nf = 0; nf < 4; ++nf)
                acc[nf] = __builtin_amdgcn_mfma_f32_16x16x32_bf16(a0, cur[ks][nf], acc[nf], 0, 0, 0);
        }
        const float* sb = sub_b + d * NEXT;
#pragma unroll
        for (int nf = 0; nf < 4; ++nf) {
            int n = w * 64 + nf * 16 + lc;
            float bias = sb[n];
#pragma unroll
            for (int r = 0; r < 4; ++r)
                h_lds[lr * 4 + r][n] = f2bf(fmaxf(acc[nf][r] + bias, 0.f));
        }
        __syncthreads();   // (b) h complete

        // LayerNorm: 32 threads per row, butterfly reduce, normalize in place
        {
            int row = t >> 5, l = t & 31;
            unsigned int* hrow = reinterpret_cast<unsigned int*>(&h_lds[row][0]);
            float s1 = 0.f, s2 = 0.f;
#pragma unroll
            for (int j = 0; j < 8; ++j) {
                unsigned int p = hrow[l + j * 32];
                float v0 = bf2f((unsigned short)(p & 0xffffu));
                float v1 = bf2f((unsigned short)(p >> 16));
                s1 += v0 + v1;
                s2 += v0 * v0 + v1 * v1;
            }
#pragma unroll
            for (int off = 16; off >= 1; off >>= 1) {
                s1 += __shfl_xor(s1, off, 32);
                s2 += __shfl_xor(s2, off, 32);
            }
            float mu = s1 * (1.f / NEXT);
            float var = s2 * (1.f / NEXT) - mu * mu;
            float rs = rsqrtf(var + 1e-5f);
            const float* g = gamma + d * NEXT;
            const float* be = beta + d * NEXT;
#pragma unroll
            for (int j = 0; j < 8; ++j) {
                int pi = l + j * 32;
                unsigned int p = hrow[pi];
                int n = pi * 2;
                float v0 = (bf2f((unsigned short)(p & 0xffffu)) - mu) * rs * g[n] + be[n];
                float v1 = (bf2f((unsigned short)(p >> 16)) - mu) * rs * g[n + 1] + be[n + 1];
                hrow[pi] = (unsigned)f2bf(v0) | ((unsigned)f2bf(v1) << 16);
            }
        }
        __syncthreads();   // (c) h normalized

        // GEMM2: (16x512)@(512x32); waves 0-3: n-tile = w&1, K-half = w>>1
        if (w < 4) {
            int kbase = (w >> 1) * 256;
            f32x4 a2 = {};
#pragma unroll
            for (int ks = 0; ks < 8; ++ks) {
                bf16x8 a = *reinterpret_cast<const bf16x8*>(&h_lds[lc][kbase + ks * 32 + lr * 8]);
                a2 = __builtin_amdgcn_mfma_f32_16x16x32_bf16(a, gq[ks], a2, 0, 0, 0);
            }
            pacc[w][lane] = a2;
        }
        __syncthreads();   // (d) partials ready

        // combine K-halves, relu, scale, accumulate into z (waves 0-1)
        if (w < 2) {
            f32x4 p0 = pacc[w][lane], p1 = pacc[w + 2][lane];
            int c = w * 16 + lc;
            float cf = coef_s[d][c], cb = cutb_s[d][c];
#pragma unroll
            for (int r = 0; r < 4; ++r) {
                int m = lr * 4 + r;
                z_lds[m][c] += fmaxf(p0[r] + p1[r] + cb, 0.f) * cf;
            }
        }
        // next iteration's barrier (a) protects z/pacc/h reuse
    };

    body(0, bqA, bqB, true);
    body(1, bqB, bqA, true);
    body(2, bqA, bqB, true);
    body(3, bqB, bqA, true);
    body(4, bqA, bqB, true);
    body(5, bqB, bqA, true);
    body(6, bqA, bqB, true);
    body(7, bqB, bqA, false);
    __syncthreads();

    // ---- tail MLP: wave w -> rows {2w, 2w+1}; half = lane>>5 picks the row ----
    {
        int half = lane >> 5, c = lane & 31;
        int row = 2 * w + half;
        int b = b0 + row;
        if (b < B) {
            // z = relu(z_acc + noise . a_mat + clb), in place
            float zz = z_lds[row][c] + clb_s[c];
#pragma unroll
            for (int a = 0; a < ANT; ++a)
                zz = fmaf(noise[((size_t)b * SC + c) * ANT + a], am_s[c * ANT + a], zz);
            z_lds[row][c] = fmaxf(zz, 0.f);

            // fc3: 98 outputs over 32 lanes (wave-synchronous LDS reuse)
            for (int o = c; o < 98; o += 32) {
                float s = W_lds[OB3 + o];
#pragma unroll
                for (int j = 0; j < SC; ++j) s = fmaf(z_lds[row][j], W_lds[OW3 + j * 98 + o], s);
                z3_s[row][o] = fmaxf(s, 0.f);
            }
            // fc4: 49 outputs
            for (int o = c; o < 49; o += 32) {
                float s = W_lds[OB4 + o];
                for (int j = 0; j < 98; ++j) s = fmaf(z3_s[row][j], W_lds[OW4 + j * 49 + o], s);
                z4_s[row][o] = fmaxf(s, 0.f);
            }
            // out: 10 logits + log_softmax (16-lane group within each half)
            float v = -INFINITY;
            if (c < 10) {
                float s = W_lds[OBO + c];
                for (int j = 0; j < 49; ++j) s = fmaf(z4_s[row][j], W_lds[OWO + j * 10 + c], s);
                v = s;
            }
            float mx = v;
#pragma unroll
            for (int off = 8; off >= 1; off >>= 1) mx = fmaxf(mx, __shfl_xor(mx, off, 16));
            float e = (c < 10) ? expf(v - mx) : 0.f;
            float ssum = e;
#pragma unroll
            for (int off = 8; off >= 1; off >>= 1) ssum += __shfl_xor(ssum, off, 16);
            if (c < 10) out[b * 10 + c] = v - mx - logf(ssum);
        }
    }
}

// ---------------------------------------------------------------------------
extern "C" void kernel_launch(void* const* d_in, const int* in_sizes, int n_in,
                              void* d_out, int out_size, void* d_ws, size_t ws_size,
                              hipStream_t stream) {
    const float* x      = (const float*)d_in[0];
    const float* noise  = (const float*)d_in[1];
    const float* sub_w  = (const float*)d_in[2];
    const float* sub_b  = (const float*)d_in[3];
    const float* ln_g   = (const float*)d_in[4];
    const float* ln_b   = (const float*)d_in[5];
    const float* cut_w  = (const float*)d_in[6];
    const float* cut_b  = (const float*)d_in[7];
    const float* b_mat  = (const float*)d_in[8];
    const float* h_mat  = (const float*)d_in[9];
    const float* a_mat  = (const float*)d_in[10];
    const float* clb    = (const float*)d_in[11];
    const float* fc3_w  = (const float*)d_in[12];
    const float* fc3_b  = (const float*)d_in[13];
    const float* fc4_w  = (const float*)d_in[14];
    const float* fc4_b  = (const float*)d_in[15];
    const float* out_w  = (const float*)d_in[16];
    const float* out_b  = (const float*)d_in[17];
    const int*   k_idx  = (const int*)d_in[18];
    float* out = (float*)d_out;

    char* ws = (char*)d_ws;
    unsigned short* sub_wT = (unsigned short*)ws;               // 1,048,576 B
    unsigned short* cut_wT = (unsigned short*)(ws + (1 << 20)); // 262,144 B

    k_prep<<<160, 256, 0, stream>>>(sub_w, cut_w, sub_wT, cut_wT);
    k_mega<<<NBLK, 512, 0, stream>>>(x, sub_wT, sub_b, ln_g, ln_b, cut_wT,
                                     cut_b, b_mat, h_mat, a_mat, k_idx,
                                     noise, clb, fc3_w, fc3_b, fc4_w, fc4_b,
                                     out_w, out_b, out);
}

// Round 12
// 49.597 us; speedup vs baseline: 1.4560x; 1.4560x over previous
//
#include <hip/hip_runtime.h>
#include <math.h>

#define B 1000
#define D 8
#define PRE 98
#define NEXT 512
#define SC 32
#define ANT 5
#define BM 32
#define NTILE 32          // 32 tiles of 32 rows
#define KP 128            // PRE padded to 128 for MFMA K-steps
#define CSTRIDE 32        // counter padding: 1 counter per 128-B line

// tail-weight LDS layout (floats)
#define OW3 0
#define OW4 3136
#define OWO 7938
#define OB3 8428
#define OB4 8526
#define OBO 8575
#define WTOT 8585

using bf16x8 = __attribute__((ext_vector_type(8))) short;
using f32x4  = __attribute__((ext_vector_type(4))) float;

static __device__ __forceinline__ unsigned short f2bf(float f) {
    union { float f; unsigned u; } v{f};
    unsigned r = (v.u + 0x7fffu + ((v.u >> 16) & 1u)) >> 16;
    return (unsigned short)r;
}

// ---------------------------------------------------------------------------
// Prep (136 blocks):
//  blocks 0..127 : sub_wT[d][n][k] (bf16, k zero-padded to 128) = sub_w[d][k][n]
//  blocks 128..135 (one per d): LN-folded GEMM2 weights + scalars:
//    cut_wT[d][c][k] = gamma[d][k] * cut_w[d][k][c]   (bf16)
//    gwsum[d][c] = sum_k gamma*cut_w ;  bwv[d][c] = sum_k beta*cut_w + cut_b
//    coef[d][c]  = b_mat * sum_a h_mat[d][k_idx[c]][a] * a_mat[c][a]
//  block 0 also zeroes the padded tile counters.
// ---------------------------------------------------------------------------
__global__ __launch_bounds__(256) void k_prep(const float* __restrict__ sub_w,
                                              const float* __restrict__ cut_w,
                                              const float* __restrict__ gamma,
                                              const float* __restrict__ beta,
                                              const float* __restrict__ cut_b,
                                              const float* __restrict__ b_mat,
                                              const float* __restrict__ h_mat,
                                              const float* __restrict__ a_mat,
                                              const int* __restrict__ k_idx,
                                              unsigned short* __restrict__ sub_wT,
                                              unsigned short* __restrict__ cut_wT,
                                              float* __restrict__ gwsum,
                                              float* __restrict__ bwv,
                                              float* __restrict__ coef,
                                              int* __restrict__ counters) {
    __shared__ __align__(16) unsigned short tile[32][128];
    __shared__ float gs_l[8][32], bs_l[8][32];
    int t = threadIdx.x, bid = blockIdx.x;
    if (bid == 0 && t < NTILE)
        __hip_atomic_store(&counters[t * CSTRIDE], 0, __ATOMIC_RELAXED,
                           __HIP_MEMORY_SCOPE_AGENT);
    if (bid < 128) {                       // sub_w: (d, n-tile of 32), k = 0..127
        int d = bid >> 4, n0 = (bid & 15) * 32;
        int nn = t & 31, kk = t >> 5;      // kk 0..7
#pragma unroll
        for (int j = 0; j < 16; ++j) {
            int k = j * 8 + kk;
            float v = (k < PRE) ? sub_w[(d * PRE + k) * NEXT + n0 + nn] : 0.f;
            tile[nn][k] = f2bf(v);
        }
        __syncthreads();
        int row = t >> 3, c0 = (t & 7) * 16;
        unsigned short* dst = sub_wT + ((size_t)(d * NEXT + n0 + row)) * KP + c0;
        *reinterpret_cast<bf16x8*>(dst)     = *reinterpret_cast<bf16x8*>(&tile[row][c0]);
        *reinterpret_cast<bf16x8*>(dst + 8) = *reinterpret_cast<bf16x8*>(&tile[row][c0 + 8]);
    } else {                               // per-d LN folding
        int d = bid - 128;
        int c = t & 31, ko = t >> 5;       // ko 0..7
        float gs = 0.f, bs = 0.f;
        for (int kk = ko; kk < NEXT; kk += 8) {
            float wv = cut_w[(size_t)(d * NEXT + kk) * SC + c];
            float g  = gamma[d * NEXT + kk];
            float be = beta[d * NEXT + kk];
            cut_wT[(size_t)(d * SC + c) * NEXT + kk] = f2bf(g * wv);
            gs += g * wv;
            bs += be * wv;
        }
        gs_l[ko][c] = gs;
        bs_l[ko][c] = bs;
        __syncthreads();
        if (t < SC) {
            float G = 0.f, Bb = 0.f;
#pragma unroll
            for (int j = 0; j < 8; ++j) { G += gs_l[j][t]; Bb += bs_l[j][t]; }
            gwsum[d * SC + t] = G;
            bwv[d * SC + t] = Bb + cut_b[d * SC + t];
            int kk = k_idx[t];
            float hv = 0.f;
#pragma unroll
            for (int a = 0; a < ANT; ++a)
                hv = fmaf(h_mat[(d * SC + kk) * ANT + a], a_mat[t * ANT + a], hv);
            coef[d * SC + t] = b_mat[d * SC + t] * hv;
        }
    }
}

// ---------------------------------------------------------------------------
// k_main (256 blocks = (d, 32-row tile), 512 thr = 8 waves):
//   gather A-frags (direct from x) + B-frags + params ->
//   GEMM1 -> h_raw to LDS + per-row stats (shuffle+LDS partials) -> BAR ->
//   GEMM2 on raw h (LN folded into weights/epilogue), coherent part stores ||
//   waves 4-7 stage tail weights -> BAR -> counter+spin -> BAR -> tail MLP.
// Only 2 compute barriers; no x_lds; no normalize pass; no gamma/beta loads.
// MFMA 16x16x32 bf16 layouts (m89/m91-verified):
//   A[m][k]: m = lane&15, k = (lane>>4)*8 + j
//   B[k][n]: n = lane&15, k = (lane>>4)*8 + j
//   D[m][n]: n = lane&15, m = (lane>>4)*4 + reg
// ---------------------------------------------------------------------------
__global__ __launch_bounds__(512) void k_main(const float* __restrict__ x,
                                              const unsigned short* __restrict__ sub_wT,
                                              const float* __restrict__ sub_b,
                                              const unsigned short* __restrict__ cut_wT,
                                              const float* __restrict__ gwsum,
                                              const float* __restrict__ bwv,
                                              const float* __restrict__ coef,
                                              const float* __restrict__ noise,
                                              const float* __restrict__ clb,
                                              const float* __restrict__ a_mat,
                                              const float* __restrict__ fc3_w,
                                              const float* __restrict__ fc3_b,
                                              const float* __restrict__ fc4_w,
                                              const float* __restrict__ fc4_b,
                                              const float* __restrict__ out_w,
                                              const float* __restrict__ out_b,
                                              float* __restrict__ part,
                                              int* __restrict__ counters,
                                              float* __restrict__ out) {
    __shared__ __align__(16) unsigned short h_lds[BM][536];   // 34304 B
    __shared__ __align__(16) float st_l[BM][2][8];            //  2048 B
    __shared__ float W_lds[WTOT];                             // 34340 B
    __shared__ float clb_s[SC], am_s[SC * ANT];
    __shared__ float z_s[4][SC];
    __shared__ float z3_s[4][98];
    __shared__ float z4_s[4][49];

    int t = threadIdx.x;
    int d = blockIdx.x >> 5;
    int tile = blockIdx.x & 31;
    int b0 = tile * BM;
    int w = t >> 6, lane = t & 63;
    int lr = lane >> 4, lc = lane & 15;
    int n0 = w * 64;

    // ---- A fragments straight from x (no LDS stage, no barrier) ----
    bf16x8 af[2][4];
#pragma unroll
    for (int mt = 0; mt < 2; ++mt) {
        int row = b0 + mt * 16 + lc;
        bool ok = row < B;
        const float* xr = x + (size_t)(ok ? row : 0) * (D * PRE) + d * PRE;
#pragma unroll
        for (int ks = 0; ks < 4; ++ks) {
            int k0 = ks * 32 + lr * 8;
            bf16x8 v;
#pragma unroll
            for (int j = 0; j < 8; ++j) {
                int k = k0 + j;
                float f = (ok && k < PRE) ? xr[k] : 0.f;
                v[j] = (short)f2bf(f);
            }
            af[mt][ks] = v;
        }
    }

    // ---- B fragments (bf16 prepped) ----
    const unsigned short* bwp = sub_wT + (size_t)d * NEXT * KP + (size_t)(n0 + lc) * KP + lr * 8;
    bf16x8 bq[4][4];
#pragma unroll
    for (int ks = 0; ks < 4; ++ks)
#pragma unroll
        for (int nf = 0; nf < 4; ++nf)
            bq[ks][nf] = *reinterpret_cast<const bf16x8*>(bwp + (size_t)nf * 16 * KP + ks * 32);

    // ---- sub_b for my 4 columns ----
    float bias[4];
#pragma unroll
    for (int nf = 0; nf < 4; ++nf) bias[nf] = sub_b[d * NEXT + n0 + nf * 16 + lc];

    // ---- GEMM2 B-frags + folded params (waves 0-3) ----
    bf16x8 gq[16];
    float gw_c = 0.f, bw_c = 0.f, cf_c = 0.f;
    if (w < 4) {
        int c = (w & 1) * 16 + lc;
        const unsigned short* cw = cut_wT + (size_t)(d * SC + c) * NEXT + lr * 8;
#pragma unroll
        for (int ks = 0; ks < 16; ++ks)
            gq[ks] = *reinterpret_cast<const bf16x8*>(cw + ks * 32);
        gw_c = gwsum[d * SC + c];
        bw_c = bwv[d * SC + c];
        cf_c = coef[d * SC + c];
    }

    // ---- GEMM1: (32x128) @ (128x512); wave -> 32 rows x 64 cols ----
    f32x4 acc[2][4] = {};
#pragma unroll
    for (int ks = 0; ks < 4; ++ks)
#pragma unroll
        for (int nf = 0; nf < 4; ++nf) {
            acc[0][nf] = __builtin_amdgcn_mfma_f32_16x16x32_bf16(af[0][ks], bq[ks][nf], acc[0][nf], 0, 0, 0);
            acc[1][nf] = __builtin_amdgcn_mfma_f32_16x16x32_bf16(af[1][ks], bq[ks][nf], acc[1][nf], 0, 0, 0);
        }

    // ---- bias+relu -> raw bf16 h + per-row LN stats partials ----
    float s1[2][4] = {}, s2[2][4] = {};
#pragma unroll
    for (int nf = 0; nf < 4; ++nf) {
        int n = n0 + nf * 16 + lc;
#pragma unroll
        for (int mt = 0; mt < 2; ++mt)
#pragma unroll
            for (int r = 0; r < 4; ++r) {
                float hv = fmaxf(acc[mt][nf][r] + bias[nf], 0.f);
                h_lds[mt * 16 + lr * 4 + r][n] = f2bf(hv);
                s1[mt][r] += hv;
                s2[mt][r] += hv * hv;
            }
    }
#pragma unroll
    for (int mt = 0; mt < 2; ++mt)
#pragma unroll
        for (int r = 0; r < 4; ++r) {
#pragma unroll
            for (int off = 8; off >= 1; off >>= 1) {
                s1[mt][r] += __shfl_xor(s1[mt][r], off, 16);
                s2[mt][r] += __shfl_xor(s2[mt][r], off, 16);
            }
            if (lc == 0) {
                int row = mt * 16 + lr * 4 + r;
                st_l[row][0][w] = s1[mt][r];
                st_l[row][1][w] = s2[mt][r];
            }
        }
    __syncthreads();   // (1) h + stats partials complete

    // ---- GEMM2 on raw h (waves 0-3) || tail-weight staging (waves 4-7) ----
    if (w < 4) {
        int mt = w >> 1;
        int c = (w & 1) * 16 + lc;
        f32x4 a2 = {};
#pragma unroll
        for (int ks = 0; ks < 16; ++ks) {
            bf16x8 a = *reinterpret_cast<const bf16x8*>(&h_lds[mt * 16 + lc][ks * 32 + lr * 8]);
            a2 = __builtin_amdgcn_mfma_f32_16x16x32_bf16(a, gq[ks], a2, 0, 0, 0);
        }
#pragma unroll
        for (int r = 0; r < 4; ++r) {
            int m = mt * 16 + lr * 4 + r;
            int b = b0 + m;
            float4 sa = *reinterpret_cast<const float4*>(&st_l[m][0][0]);
            float4 sb = *reinterpret_cast<const float4*>(&st_l[m][0][4]);
            float4 qa = *reinterpret_cast<const float4*>(&st_l[m][1][0]);
            float4 qb = *reinterpret_cast<const float4*>(&st_l[m][1][4]);
            float S1 = (sa.x + sa.y) + (sa.z + sa.w) + (sb.x + sb.y) + (sb.z + sb.w);
            float S2 = (qa.x + qa.y) + (qa.z + qa.w) + (qb.x + qb.y) + (qb.z + qb.w);
            float mu = S1 * (1.f / NEXT);
            float var = S2 * (1.f / NEXT) - mu * mu;
            float rs = rsqrtf(var + 1e-5f);
            float cutv = fmaxf(rs * (a2[r] - mu * gw_c) + bw_c, 0.f) * cf_c;
            if (b < B)
                __hip_atomic_store(&part[((size_t)b * D + d) * SC + c], cutv,
                                   __ATOMIC_RELAXED, __HIP_MEMORY_SCOPE_AGENT);
        }
    } else {
        int tt = t - 256;  // 0..255
        for (int i = tt; i < 3136; i += 256) W_lds[OW3 + i] = fc3_w[i];
        for (int i = tt; i < 4802; i += 256) W_lds[OW4 + i] = fc4_w[i];
        for (int i = tt; i < 490; i += 256)  W_lds[OWO + i] = out_w[i];
        if (tt < 98) W_lds[OB3 + tt] = fc3_b[tt];
        if (tt < 49) W_lds[OB4 + tt] = fc4_b[tt];
        if (tt < 10) W_lds[OBO + tt] = out_b[tt];
        if (tt >= 128 && tt < 128 + SC) clb_s[tt - 128] = clb[tt - 128];
        if (tt >= 160 && tt < 160 + SC * ANT) am_s[tt - 160] = a_mat[tt - 160];
    }

    // ---- per-tile sync: relaxed RMW + spin on padded private line ----
    __syncthreads();   // (2) drains coherent part stores (vmcnt) + W_lds
    if (t == 0) {
        __hip_atomic_fetch_add(&counters[tile * CSTRIDE], 1,
                               __ATOMIC_RELAXED, __HIP_MEMORY_SCOPE_AGENT);
        while (__hip_atomic_load(&counters[tile * CSTRIDE],
                                 __ATOMIC_RELAXED, __HIP_MEMORY_SCOPE_AGENT) < D)
            __builtin_amdgcn_s_sleep(2);
    }
    __syncthreads();   // (3)

    // ---- tail MLP: this block handles rows d*4 .. d*4+3; wave w<4 -> one row ----
    if (w < 4) {
        int b = b0 + d * 4 + w;
        if (b < B) {
            int c = lane & 31, dg = lane >> 5;   // dg in {0,1}
            float s = 0.f;
#pragma unroll
            for (int i = 0; i < 4; ++i)
                s += __hip_atomic_load(&part[((size_t)b * D + (dg + 2 * i)) * SC + c],
                                       __ATOMIC_RELAXED, __HIP_MEMORY_SCOPE_AGENT);
            s += __shfl_xor(s, 32);
            if (lane < 32) {
                float zz = s + clb_s[c];
#pragma unroll
                for (int a = 0; a < ANT; ++a)
                    zz = fmaf(noise[(b * SC + c) * ANT + a], am_s[c * ANT + a], zz);
                z_s[w][c] = fmaxf(zz, 0.f);
            }
            for (int o = lane; o < 98; o += 64) {
                float s3 = W_lds[OB3 + o];
#pragma unroll
                for (int j = 0; j < SC; ++j) s3 = fmaf(z_s[w][j], W_lds[OW3 + j * 98 + o], s3);
                z3_s[w][o] = fmaxf(s3, 0.f);
            }
            if (lane < 49) {
                float s4 = W_lds[OB4 + lane];
                for (int j = 0; j < 98; ++j) s4 = fmaf(z3_s[w][j], W_lds[OW4 + j * 49 + lane], s4);
                z4_s[w][lane] = fmaxf(s4, 0.f);
            }
            float v = -INFINITY;
            if (lane < 10) {
                float so = W_lds[OBO + lane];
                for (int j = 0; j < 49; ++j) so = fmaf(z4_s[w][j], W_lds[OWO + j * 10 + lane], so);
                v = so;
            }
            float mx = v;
#pragma unroll
            for (int off = 8; off >= 1; off >>= 1) mx = fmaxf(mx, __shfl_xor(mx, off, 16));
            float e = (lane < 10) ? expf(v - mx) : 0.f;
            float ssum = e;
#pragma unroll
            for (int off = 8; off >= 1; off >>= 1) ssum += __shfl_xor(ssum, off, 16);
            if (lane < 10) out[b * 10 + lane] = v - mx - logf(ssum);
        }
    }
}

// ---------------------------------------------------------------------------
extern "C" void kernel_launch(void* const* d_in, const int* in_sizes, int n_in,
                              void* d_out, int out_size, void* d_ws, size_t ws_size,
                              hipStream_t stream) {
    const float* x      = (const float*)d_in[0];
    const float* noise  = (const float*)d_in[1];
    const float* sub_w  = (const float*)d_in[2];
    const float* sub_b  = (const float*)d_in[3];
    const float* ln_g   = (const float*)d_in[4];
    const float* ln_b   = (const float*)d_in[5];
    const float* cut_w  = (const float*)d_in[6];
    const float* cut_b  = (const float*)d_in[7];
    const float* b_mat  = (const float*)d_in[8];
    const float* h_mat  = (const float*)d_in[9];
    const float* a_mat  = (const float*)d_in[10];
    const float* clb    = (const float*)d_in[11];
    const float* fc3_w  = (const float*)d_in[12];
    const float* fc3_b  = (const float*)d_in[13];
    const float* fc4_w  = (const float*)d_in[14];
    const float* fc4_b  = (const float*)d_in[15];
    const float* out_w  = (const float*)d_in[16];
    const float* out_b  = (const float*)d_in[17];
    const int*   k_idx  = (const int*)d_in[18];
    float* out = (float*)d_out;

    char* ws = (char*)d_ws;
    float* part            = (float*)ws;                          // 1,024,000 B [b][d][c]
    unsigned short* sub_wT = (unsigned short*)(ws + (1 << 20));   // 1,048,576 B
    unsigned short* cut_wT = (unsigned short*)(ws + (2 << 20));   //   262,144 B
    float* gwsum           = (float*)(ws + (2 << 20) + 262144);   //     1,024 B
    float* bwv             = (float*)(ws + (2 << 20) + 263168);   //     1,024 B
    float* coef            = (float*)(ws + (2 << 20) + 264192);   //     1,024 B
    int* counters          = (int*)(ws + (2 << 20) + 266240);     //     4,096 B

    k_prep<<<136, 256, 0, stream>>>(sub_w, cut_w, ln_g, ln_b, cut_b, b_mat,
                                    h_mat, a_mat, k_idx, sub_wT, cut_wT,
                                    gwsum, bwv, coef, counters);
    k_main<<<D * NTILE, 512, 0, stream>>>(x, sub_wT, sub_b, cut_wT, gwsum, bwv,
                                          coef, noise, clb, a_mat, fc3_w, fc3_b,
                                          fc4_w, fc4_b, out_w, out_b, part,
                                          counters, out);
}

// Round 13
// 44.048 us; speedup vs baseline: 1.6394x; 1.1260x over previous
//
#include <hip/hip_runtime.h>
#include <math.h>

#define B 1000
#define D 8
#define PRE 98
#define NEXT 512
#define SC 32
#define ANT 5
#define BM 16
#define NTILE 63          // 63 tiles of 16 rows (last partial: 992..999)
#define KP 128            // PRE padded to 128 for MFMA K-steps
#define CSTRIDE 32        // counter padding: 1 counter per 128-B line

// tail-weight LDS layout (floats)
#define OW3 0
#define OW4 3136
#define OWO 7938
#define OB3 8428
#define OB4 8526
#define OBO 8575
#define WTOT 8585

using bf16x8 = __attribute__((ext_vector_type(8))) short;
using f32x4  = __attribute__((ext_vector_type(4))) float;

static __device__ __forceinline__ unsigned short f2bf(float f) {
    union { float f; unsigned u; } v{f};
    unsigned r = (v.u + 0x7fffu + ((v.u >> 16) & 1u)) >> 16;
    return (unsigned short)r;
}

// ---------------------------------------------------------------------------
// Prep (136 blocks) — identical numerics to R12 (absmax-proven):
//  blocks 0..127 : sub_wT[d][n][k] (bf16, k zero-padded to 128) = sub_w[d][k][n]
//  blocks 128..135 (one per d): LN-folded GEMM2 weights + scalars:
//    cut_wT[d][c][k] = gamma[d][k] * cut_w[d][k][c]   (bf16)
//    gwsum[d][c] = sum_k gamma*cut_w ;  bwv[d][c] = sum_k beta*cut_w + cut_b
//    coef[d][c]  = b_mat * sum_a h_mat[d][k_idx[c]][a] * a_mat[c][a]
//  block 0 also zeroes the padded tile counters.
// ---------------------------------------------------------------------------
__global__ __launch_bounds__(256) void k_prep(const float* __restrict__ sub_w,
                                              const float* __restrict__ cut_w,
                                              const float* __restrict__ gamma,
                                              const float* __restrict__ beta,
                                              const float* __restrict__ cut_b,
                                              const float* __restrict__ b_mat,
                                              const float* __restrict__ h_mat,
                                              const float* __restrict__ a_mat,
                                              const int* __restrict__ k_idx,
                                              unsigned short* __restrict__ sub_wT,
                                              unsigned short* __restrict__ cut_wT,
                                              float* __restrict__ gwsum,
                                              float* __restrict__ bwv,
                                              float* __restrict__ coef,
                                              int* __restrict__ counters) {
    __shared__ __align__(16) unsigned short tile[32][128];
    __shared__ float gs_l[8][32], bs_l[8][32];
    int t = threadIdx.x, bid = blockIdx.x;
    if (bid == 0 && t < NTILE)
        __hip_atomic_store(&counters[t * CSTRIDE], 0, __ATOMIC_RELAXED,
                           __HIP_MEMORY_SCOPE_AGENT);
    if (bid < 128) {                       // sub_w: (d, n-tile of 32), k = 0..127
        int d = bid >> 4, n0 = (bid & 15) * 32;
        int nn = t & 31, kk = t >> 5;      // kk 0..7
#pragma unroll
        for (int j = 0; j < 16; ++j) {
            int k = j * 8 + kk;
            float v = (k < PRE) ? sub_w[(d * PRE + k) * NEXT + n0 + nn] : 0.f;
            tile[nn][k] = f2bf(v);
        }
        __syncthreads();
        int row = t >> 3, c0 = (t & 7) * 16;
        unsigned short* dst = sub_wT + ((size_t)(d * NEXT + n0 + row)) * KP + c0;
        *reinterpret_cast<bf16x8*>(dst)     = *reinterpret_cast<bf16x8*>(&tile[row][c0]);
        *reinterpret_cast<bf16x8*>(dst + 8) = *reinterpret_cast<bf16x8*>(&tile[row][c0 + 8]);
    } else {                               // per-d LN folding
        int d = bid - 128;
        int c = t & 31, ko = t >> 5;       // ko 0..7
        float gs = 0.f, bs = 0.f;
        for (int kk = ko; kk < NEXT; kk += 8) {
            float wv = cut_w[(size_t)(d * NEXT + kk) * SC + c];
            float g  = gamma[d * NEXT + kk];
            float be = beta[d * NEXT + kk];
            cut_wT[(size_t)(d * SC + c) * NEXT + kk] = f2bf(g * wv);
            gs += g * wv;
            bs += be * wv;
        }
        gs_l[ko][c] = gs;
        bs_l[ko][c] = bs;
        __syncthreads();
        if (t < SC) {
            float G = 0.f, Bb = 0.f;
#pragma unroll
            for (int j = 0; j < 8; ++j) { G += gs_l[j][t]; Bb += bs_l[j][t]; }
            gwsum[d * SC + t] = G;
            bwv[d * SC + t] = Bb + cut_b[d * SC + t];
            int kk = k_idx[t];
            float hv = 0.f;
#pragma unroll
            for (int a = 0; a < ANT; ++a)
                hv = fmaf(h_mat[(d * SC + kk) * ANT + a], a_mat[t * ANT + a], hv);
            coef[d * SC + t] = b_mat[d * SC + t] * hv;
        }
    }
}

// ---------------------------------------------------------------------------
// k_main (504 blocks = (d, 16-row tile), 512 thr = 8 waves, ~2 blocks/CU):
//   stage x (coalesced) -> BAR -> GEMM1 (loads in-loop, small live set) ->
//   h_raw + LN stats -> BAR -> GEMM2 on raw h (LN folded, waves 0-1) ||
//   tail-weight staging (waves 2-7) -> BAR -> counter+spin -> BAR ->
//   tail MLP for this block's 2 rows.
// LDS ~59 KB -> 2 blocks/CU; __launch_bounds__(512,4) caps VGPR at 128 so
// nothing spills (no large fragment arrays are kept live).
// MFMA 16x16x32 bf16 layouts (m89/m91-verified):
//   A[m][k]: m = lane&15, k = (lane>>4)*8 + j
//   B[k][n]: n = lane&15, k = (lane>>4)*8 + j
//   D[m][n]: n = lane&15, m = (lane>>4)*4 + reg
// ---------------------------------------------------------------------------
__global__ __launch_bounds__(512, 4) void k_main(const float* __restrict__ x,
                                                 const unsigned short* __restrict__ sub_wT,
                                                 const float* __restrict__ sub_b,
                                                 const unsigned short* __restrict__ cut_wT,
                                                 const float* __restrict__ gwsum,
                                                 const float* __restrict__ bwv,
                                                 const float* __restrict__ coef,
                                                 const float* __restrict__ noise,
                                                 const float* __restrict__ clb,
                                                 const float* __restrict__ a_mat,
                                                 const float* __restrict__ fc3_w,
                                                 const float* __restrict__ fc3_b,
                                                 const float* __restrict__ fc4_w,
                                                 const float* __restrict__ fc4_b,
                                                 const float* __restrict__ out_w,
                                                 const float* __restrict__ out_b,
                                                 float* __restrict__ part,
                                                 int* __restrict__ counters,
                                                 float* __restrict__ out) {
    __shared__ __align__(16) unsigned short x_lds[BM][136];   //  4352 B
    __shared__ __align__(16) unsigned short h_lds[BM][536];   // 17152 B
    __shared__ __align__(16) float st_l[BM][2][8];            //  1024 B
    __shared__ float W_lds[WTOT];                             // 34340 B
    __shared__ float clb_s[SC], am_s[SC * ANT];
    __shared__ float z_s[2][SC];
    __shared__ float z3_s[2][98];
    __shared__ float z4_s[2][49];

    int t = threadIdx.x;
    int bid = blockIdx.x;
    int d = bid / NTILE;
    int tile = bid - d * NTILE;
    int b0 = tile * BM;
    int w = t >> 6, lane = t & 63;
    int lr = lane >> 4, lc = lane & 15;
    int n0 = w * 64;

    // ---- stage x tile -> bf16 LDS (coalesced), zero rows>=B ----
    for (int idx = t; idx < BM * PRE; idx += 512) {
        int r = idx / PRE, i = idx - r * PRE;
        int b = b0 + r;
        float v = (b < B) ? x[(size_t)b * (D * PRE) + d * PRE + i] : 0.f;
        x_lds[r][i] = f2bf(v);
    }
    // zero the k-pad region [98,136)
    for (int idx = t; idx < BM * 38; idx += 512) {
        int r = idx / 38, i = idx - r * 38;
        x_lds[r][98 + i] = 0;
    }

    // ---- per-thread scalars (small, no pressure) ----
    float bias[4];
#pragma unroll
    for (int nf = 0; nf < 4; ++nf) bias[nf] = sub_b[d * NEXT + n0 + nf * 16 + lc];
    float gw_c = 0.f, bw_c = 0.f, cf_c = 0.f;
    if (w < 2) {
        int c = w * 16 + lc;
        gw_c = gwsum[d * SC + c];
        bw_c = bwv[d * SC + c];
        cf_c = coef[d * SC + c];
    }
    __syncthreads();   // (0) x ready

    // ---- GEMM1: (16x128)@(128x512); wave -> 16 rows x 64 cols ----
    // B loads in-loop: live set stays small; 4 waves/SIMD hide latency.
    const unsigned short* bwp = sub_wT + (size_t)d * NEXT * KP + (size_t)(n0 + lc) * KP + lr * 8;
    f32x4 acc[4] = {};
#pragma unroll
    for (int ks = 0; ks < 4; ++ks) {
        bf16x8 a = *reinterpret_cast<const bf16x8*>(&x_lds[lc][ks * 32 + lr * 8]);
#pragma unroll
        for (int nf = 0; nf < 4; ++nf) {
            bf16x8 bq = *reinterpret_cast<const bf16x8*>(bwp + (size_t)nf * 16 * KP + ks * 32);
            acc[nf] = __builtin_amdgcn_mfma_f32_16x16x32_bf16(a, bq, acc[nf], 0, 0, 0);
        }
    }

    // ---- bias+relu -> raw bf16 h + per-row LN stats ----
    float s1[4] = {}, s2[4] = {};
#pragma unroll
    for (int nf = 0; nf < 4; ++nf) {
        int n = n0 + nf * 16 + lc;
#pragma unroll
        for (int r = 0; r < 4; ++r) {
            float hv = fmaxf(acc[nf][r] + bias[nf], 0.f);
            h_lds[lr * 4 + r][n] = f2bf(hv);
            s1[r] += hv;
            s2[r] += hv * hv;
        }
    }
#pragma unroll
    for (int r = 0; r < 4; ++r) {
#pragma unroll
        for (int off = 8; off >= 1; off >>= 1) {
            s1[r] += __shfl_xor(s1[r], off, 16);
            s2[r] += __shfl_xor(s2[r], off, 16);
        }
        if (lc == 0) {
            int row = lr * 4 + r;
            st_l[row][0][w] = s1[r];
            st_l[row][1][w] = s2[r];
        }
    }
    __syncthreads();   // (1) h + stats complete

    // ---- GEMM2 on raw h (waves 0-1, 16 cols each, full K=512)
    //      || tail-weight staging (waves 2-7) ----
    if (w < 2) {
        int c = w * 16 + lc;
        const unsigned short* cw = cut_wT + (size_t)(d * SC + c) * NEXT + lr * 8;
        f32x4 a2 = {};
#pragma unroll
        for (int ks = 0; ks < 16; ++ks) {
            bf16x8 a = *reinterpret_cast<const bf16x8*>(&h_lds[lc][ks * 32 + lr * 8]);
            bf16x8 g = *reinterpret_cast<const bf16x8*>(cw + ks * 32);
            a2 = __builtin_amdgcn_mfma_f32_16x16x32_bf16(a, g, a2, 0, 0, 0);
        }
#pragma unroll
        for (int r = 0; r < 4; ++r) {
            int m = lr * 4 + r;
            int b = b0 + m;
            float4 sa = *reinterpret_cast<const float4*>(&st_l[m][0][0]);
            float4 sb = *reinterpret_cast<const float4*>(&st_l[m][0][4]);
            float4 qa = *reinterpret_cast<const float4*>(&st_l[m][1][0]);
            float4 qb = *reinterpret_cast<const float4*>(&st_l[m][1][4]);
            float S1 = (sa.x + sa.y) + (sa.z + sa.w) + (sb.x + sb.y) + (sb.z + sb.w);
            float S2 = (qa.x + qa.y) + (qa.z + qa.w) + (qb.x + qb.y) + (qb.z + qb.w);
            float mu = S1 * (1.f / NEXT);
            float var = S2 * (1.f / NEXT) - mu * mu;
            float rs = rsqrtf(var + 1e-5f);
            float cutv = fmaxf(rs * (a2[r] - mu * gw_c) + bw_c, 0.f) * cf_c;
            if (b < B)
                __hip_atomic_store(&part[((size_t)b * D + d) * SC + c], cutv,
                                   __ATOMIC_RELAXED, __HIP_MEMORY_SCOPE_AGENT);
        }
    } else {
        int tt = t - 128;  // 0..383
        for (int i = tt; i < 3136; i += 384) W_lds[OW3 + i] = fc3_w[i];
        for (int i = tt; i < 4802; i += 384) W_lds[OW4 + i] = fc4_w[i];
        for (int i = tt; i < 490; i += 384)  W_lds[OWO + i] = out_w[i];
        if (tt < 98) W_lds[OB3 + tt] = fc3_b[tt];
        if (tt < 49) W_lds[OB4 + tt] = fc4_b[tt];
        if (tt < 10) W_lds[OBO + tt] = out_b[tt];
        if (tt >= 128 && tt < 128 + SC) clb_s[tt - 128] = clb[tt - 128];
        if (tt >= 160 && tt < 160 + SC * ANT) am_s[tt - 160] = a_mat[tt - 160];
    }

    // ---- per-tile sync: relaxed RMW + spin on padded private line ----
    __syncthreads();   // (2) drains coherent part stores (vmcnt) + W_lds
    if (t == 0) {
        __hip_atomic_fetch_add(&counters[tile * CSTRIDE], 1,
                               __ATOMIC_RELAXED, __HIP_MEMORY_SCOPE_AGENT);
        while (__hip_atomic_load(&counters[tile * CSTRIDE],
                                 __ATOMIC_RELAXED, __HIP_MEMORY_SCOPE_AGENT) < D)
            __builtin_amdgcn_s_sleep(2);
    }
    __syncthreads();   // (3)

    // ---- tail MLP: this block handles rows d*2 and d*2+1; waves 0-1 ----
    if (w < 2) {
        int b = b0 + d * 2 + w;
        if (b < B) {
            int c = lane & 31, dg = lane >> 5;   // dg in {0,1}
            float s = 0.f;
#pragma unroll
            for (int i = 0; i < 4; ++i)
                s += __hip_atomic_load(&part[((size_t)b * D + (dg + 2 * i)) * SC + c],
                                       __ATOMIC_RELAXED, __HIP_MEMORY_SCOPE_AGENT);
            s += __shfl_xor(s, 32);
            if (lane < 32) {
                float zz = s + clb_s[c];
#pragma unroll
                for (int a = 0; a < ANT; ++a)
                    zz = fmaf(noise[((size_t)b * SC + c) * ANT + a], am_s[c * ANT + a], zz);
                z_s[w][c] = fmaxf(zz, 0.f);
            }
            // fc3: 98 outputs over 64 lanes
            for (int o = lane; o < 98; o += 64) {
                float s3 = W_lds[OB3 + o];
#pragma unroll
                for (int j = 0; j < SC; ++j) s3 = fmaf(z_s[w][j], W_lds[OW3 + j * 98 + o], s3);
                z3_s[w][o] = fmaxf(s3, 0.f);
            }
            // fc4: 49 outputs
            if (lane < 49) {
                float s4 = W_lds[OB4 + lane];
                for (int j = 0; j < 98; ++j) s4 = fmaf(z3_s[w][j], W_lds[OW4 + j * 49 + lane], s4);
                z4_s[w][lane] = fmaxf(s4, 0.f);
            }
            // out: 10 logits + log_softmax (16-lane shuffle group)
            float v = -INFINITY;
            if (lane < 10) {
                float so = W_lds[OBO + lane];
                for (int j = 0; j < 49; ++j) so = fmaf(z4_s[w][j], W_lds[OWO + j * 10 + lane], so);
                v = so;
            }
            float mx = v;
#pragma unroll
            for (int off = 8; off >= 1; off >>= 1) mx = fmaxf(mx, __shfl_xor(mx, off, 16));
            float e = (lane < 10) ? expf(v - mx) : 0.f;
            float ssum = e;
#pragma unroll
            for (int off = 8; off >= 1; off >>= 1) ssum += __shfl_xor(ssum, off, 16);
            if (lane < 10) out[b * 10 + lane] = v - mx - logf(ssum);
        }
    }
}

// ---------------------------------------------------------------------------
extern "C" void kernel_launch(void* const* d_in, const int* in_sizes, int n_in,
                              void* d_out, int out_size, void* d_ws, size_t ws_size,
                              hipStream_t stream) {
    const float* x      = (const float*)d_in[0];
    const float* noise  = (const float*)d_in[1];
    const float* sub_w  = (const float*)d_in[2];
    const float* sub_b  = (const float*)d_in[3];
    const float* ln_g   = (const float*)d_in[4];
    const float* ln_b   = (const float*)d_in[5];
    const float* cut_w  = (const float*)d_in[6];
    const float* cut_b  = (const float*)d_in[7];
    const float* b_mat  = (const float*)d_in[8];
    const float* h_mat  = (const float*)d_in[9];
    const float* a_mat  = (const float*)d_in[10];
    const float* clb    = (const float*)d_in[11];
    const float* fc3_w  = (const float*)d_in[12];
    const float* fc3_b  = (const float*)d_in[13];
    const float* fc4_w  = (const float*)d_in[14];
    const float* fc4_b  = (const float*)d_in[15];
    const float* out_w  = (const float*)d_in[16];
    const float* out_b  = (const float*)d_in[17];
    const int*   k_idx  = (const int*)d_in[18];
    float* out = (float*)d_out;

    char* ws = (char*)d_ws;
    float* part            = (float*)ws;                          // 1,024,000 B [b][d][c]
    unsigned short* sub_wT = (unsigned short*)(ws + (1 << 20));   // 1,048,576 B
    unsigned short* cut_wT = (unsigned short*)(ws + (2 << 20));   //   262,144 B
    float* gwsum           = (float*)(ws + (2 << 20) + 262144);   //     1,024 B
    float* bwv             = (float*)(ws + (2 << 20) + 263168);   //     1,024 B
    float* coef            = (float*)(ws + (2 << 20) + 264192);   //     1,024 B
    int* counters          = (int*)(ws + (2 << 20) + 266240);     //     8,064 B

    k_prep<<<136, 256, 0, stream>>>(sub_w, cut_w, ln_g, ln_b, cut_b, b_mat,
                                    h_mat, a_mat, k_idx, sub_wT, cut_wT,
                                    gwsum, bwv, coef, counters);
    k_main<<<D * NTILE, 512, 0, stream>>>(x, sub_wT, sub_b, cut_wT, gwsum, bwv,
                                          coef, noise, clb, a_mat, fc3_w, fc3_b,
                                          fc4_w, fc4_b, out_w, out_b, part,
                                          counters, out);
}